// Round 5
// baseline (97149.945 us; speedup 1.0000x reference)
//
#include <hip/hip_runtime.h>

typedef float f4 __attribute__((ext_vector_type(4)));

#define Nn 256
#define Mm 512
#define Dd 64
#define EPSF 1e-6f
#define INFF 1e30f
#define BC 8
#define NCHUNK (Nn / BC)   // 32
#define R 8                // rows per wave-stage
#define WV 8               // waves per block
#define NB 8               // blocks (stages = NB*WV = 64)
#define NSLOT (NCHUNK + WV - 1)  // 39

// workspace layout (float offsets)
#define OFF_D     0                      // d[m][n]  512*256
#define OFF_QC    131072                 // qc[nb][j]=q[j][nb]  256*257
#define OFF_P     (OFF_QC + 65792)       // p[257]
#define OFF_WT    (OFF_P + 260)          // wT[t][n]  256*256
#define OFF_WS    (OFF_WT + 65536)       // W[n] col sums  256
#define OFF_FW    (OFF_WS + 256)         // fw[t] final weights  256
#define OFF_CB    (OFF_FW + 256)         // 7 boundary cbar buffers, each 256*256
#define OFF_CROW  (OFF_CB + 7 * 65536)   // crow[b][256], 8*256
#define OFF_FLAG  (OFF_CROW + NB * Nn)   // flags[b][chunk], 7*32 ints

// ---------------- LLC-coherent (sc0 sc1) helpers — all BLOCKING ----------------
__device__ __forceinline__ int llc_load_int(const int* p) {
  int v;
  asm volatile("global_load_dword %0, %1, off sc0 sc1\n\ts_waitcnt vmcnt(0)"
               : "=v"(v) : "v"(p) : "memory");
  return v;
}
__device__ __forceinline__ void llc_store_int(int* p, int v) {
  asm volatile("global_store_dword %0, %1, off sc0 sc1" :: "v"(p), "v"(v) : "memory");
}
// 8 cbar rows + 2 crow vectors, one blocking round trip
__device__ __forceinline__ void llc_load10(const float* b0, const float* cp,
                                           f4 c[BC], f4& pl, f4& ph) {
  const float* b1 = b0 + 4 * Nn;
  asm volatile(
    "global_load_dwordx4 %8, %12, off sc0 sc1\n\t"
    "global_load_dwordx4 %9, %12, off offset:16 sc0 sc1\n\t"
    "global_load_dwordx4 %0, %10, off sc0 sc1\n\t"
    "global_load_dwordx4 %1, %10, off offset:1024 sc0 sc1\n\t"
    "global_load_dwordx4 %2, %10, off offset:2048 sc0 sc1\n\t"
    "global_load_dwordx4 %3, %10, off offset:3072 sc0 sc1\n\t"
    "global_load_dwordx4 %4, %11, off sc0 sc1\n\t"
    "global_load_dwordx4 %5, %11, off offset:1024 sc0 sc1\n\t"
    "global_load_dwordx4 %6, %11, off offset:2048 sc0 sc1\n\t"
    "global_load_dwordx4 %7, %11, off offset:3072 sc0 sc1\n\t"
    "s_waitcnt vmcnt(0)"
    : "=v"(c[0]), "=v"(c[1]), "=v"(c[2]), "=v"(c[3]),
      "=v"(c[4]), "=v"(c[5]), "=v"(c[6]), "=v"(c[7]),
      "=v"(pl), "=v"(ph)
    : "v"(b0), "v"(b1), "v"(cp)
    : "memory");
}
__device__ __forceinline__ void llc_store16(float* p, f4 v) {
  asm volatile("global_store_dwordx4 %0, %1, off sc0 sc1" :: "v"(p), "v"(v) : "memory");
}
__device__ __forceinline__ void vm_drain() {
  asm volatile("s_waitcnt vmcnt(0)" ::: "memory");
}
__device__ __forceinline__ float rdlane(float v, int l) {
  return __int_as_float(__builtin_amdgcn_readlane(__float_as_int(v), l));
}

// ---------------- fused setup: dist + q-transpose + flag/Wsum init ----------------
__global__ __launch_bounds__(256) void k_setup(const float* __restrict__ x,
                                               const float* __restrict__ y,
                                               const float* __restrict__ q,
                                               float* __restrict__ ws) {
  int bid = blockIdx.x, tid = threadIdx.x;
  if (bid < Mm) {                      // pairwise L2 distances, row bid
    __shared__ float xs[Dd];
    if (tid < Dd) xs[tid] = x[bid * Dd + tid];
    __syncthreads();
    const float4* y4 = (const float4*)(y + tid * Dd);
    float acc = 0.f;
#pragma unroll
    for (int k = 0; k < Dd / 4; k++) {
      float4 v = y4[k];
      float a0 = xs[4*k+0] - v.x, a1 = xs[4*k+1] - v.y;
      float a2 = xs[4*k+2] - v.z, a3 = xs[4*k+3] - v.w;
      acc += a0*a0 + a1*a1 + a2*a2 + a3*a3;
    }
    ws[OFF_D + bid * Nn + tid] = sqrtf(acc);
  } else if (bid < Mm + 257) {         // transpose q -> qc[nb][j]
    int j = bid - Mm;
    ws[OFF_QC + tid * 257 + j] = q[j * Nn + tid];
  } else {                             // init flags + Wsum
    if (tid < (NB - 1) * NCHUNK) ((int*)(ws + OFF_FLAG))[tid] = 0;
    ws[OFF_WS + tid] = 0.f;
  }
}

// blocked sequential reachability scan
__global__ __launch_bounds__(256) void k_reach(const float* __restrict__ qc, float* __restrict__ p_out) {
  __shared__ float p[257];
  __shared__ float vsnap[64];
  __shared__ float qtile[64][65];
  int tid = threadIdx.x;
  p[tid] = (tid == 0) ? 1.f : 0.f;
  if (tid == 0) p[256] = 0.f;
  __syncthreads();
  for (int g = 0; g < 4; g++) {
    int g0 = g * 64;
    for (int z = 0; z < 16; z++) {
      int idx = tid + z * 256, k = idx >> 6, l = idx & 63;
      qtile[k][l] = qc[(g0 + k) * 257 + g0 + l];
    }
    __syncthreads();
    if (tid < 64) {
      float pv = p[g0 + tid];
      for (int k = 0; k < 64; k++) {
        float v = __shfl(pv, k, 64);
        if (tid == k) vsnap[k] = v;
        pv += v * qtile[k][tid];
      }
    }
    __syncthreads();
    float acc = p[tid];
    float acc2 = (tid == 0) ? p[256] : 0.f;
    for (int k = 0; k < 64; k++) {
      float v = vsnap[k];
      acc += v * qc[(g0 + k) * 257 + tid];
      if (tid == 0) acc2 += v * qc[(g0 + k) * 257 + 256];
    }
    __syncthreads();
    p[tid] = acc;
    if (tid == 0) p[256] = acc2;
    __syncthreads();
  }
  p_out[tid] = p[tid];
  if (tid == 0) p_out[256] = p[256];
}

__global__ __launch_bounds__(256) void k_wbuild(const float* __restrict__ qc, const float* __restrict__ p,
                                                float* __restrict__ wT, float* __restrict__ Wsum,
                                                float* __restrict__ fw) {
  int t = blockIdx.x, n = threadIdx.x;
  float v = 0.f;
  if (t < n) v = p[t] * qc[t * 257 + n] / (p[n] + EPSF);
  wT[t * Nn + n] = v;
  if (v != 0.f) atomicAdd(&Wsum[n], v);
  if (n == 0) fw[t] = p[t] * qc[t * 257 + 256] / (p[Nn] + EPSF);
}

// ---------------- main: 8 blocks x 8 wave-stages, LDS systolic handoff,
// cross-block handoff = R2-proven flag protocol (poll dword, load data once) ----
__global__ __launch_bounds__(512, 2) void k_main(const float* __restrict__ d,
                                                 const float* __restrict__ wT,
                                                 const float* __restrict__ Wsum,
                                                 const float* __restrict__ fw,
                                                 float* __restrict__ cbarB,
                                                 float* __restrict__ crowG,
                                                 int* __restrict__ flags,
                                                 float* __restrict__ out) {
  const int b = blockIdx.x;
  const int tid = threadIdx.x;
  const int w = tid >> 6;            // wave-stage within block, 0..7
  const int lane = tid & 63;         // owns cols 4*lane..4*lane+3
  const int m0 = (b * WV + w) * R;
  const bool isStage0 = (b == 0 && w == 0);

  __shared__ __align__(16) float LB[WV - 1][BC][Nn];   // 57344 B
  __shared__ __align__(16) float crowLB[WV - 1][BC];

  f4 dl[R], S[R];
#pragma unroll
  for (int r = 0; r < R; r++) {
    dl[r] = *(const f4*)(d + (m0 + r) * Nn + 4 * lane);
    S[r] = (f4){0.f, 0.f, 0.f, 0.f};
  }
  f4 Wt = *(const f4*)(Wsum + 4 * lane);
  float facc = 0.f;                  // final-reduction partial (b==NB-1, w==WV-1)

#pragma clang loop unroll(disable)
  for (int tau = 0; tau < NSLOT; tau++) {
    const int j = tau - w;
    const bool act = (j >= 0 && j < NCHUNK);
    f4 c[BC], cpl, cph, wv[BC];

    // ---- phase 1: acquire input ----
    if (act) {
      if (w == 0) {
        if (b == 0) {
          cpl = (f4){INFF, INFF, INFF, INFF}; cph = cpl;
#pragma unroll
          for (int tt = 0; tt < BC; tt++) c[tt] = cpl;
        } else {
          const int* fp = flags + (b - 1) * NCHUNK + j;
          while (llc_load_int(fp) == 0) __builtin_amdgcn_s_sleep(1);
          llc_load10(cbarB + (size_t)(b - 1) * 65536 + j * BC * Nn + 4 * lane,
                     crowG + (b - 1) * Nn + j * BC, c, cpl, cph);
        }
      } else {
#pragma unroll
        for (int tt = 0; tt < BC; tt++) c[tt] = *(const f4*)&LB[w - 1][tt][4 * lane];
        cpl = *(const f4*)&crowLB[w - 1][0];
        cph = *(const f4*)&crowLB[w - 1][4];
      }
#pragma unroll
      for (int tt = 0; tt < BC; tt++)
        wv[tt] = *(const f4*)(wT + (j * BC + tt) * Nn + 4 * lane);
    }
    __syncthreads();

    // ---- phase 2: compute + hand off ----
    if (act) {
      f4 clast4;
      const bool isJ0 = (j == 0);
#pragma unroll
      for (int tt = 0; tt < BC; tt++) {
        const int owner = 2 * j + (tt >> 2);
        const int comp = tt & 3;
        const bool isT0 = isJ0 && (tt == 0);
        float up = (tt < 4) ? cpl[comp] : cph[comp];
        float prcMin = up, prcVal = up;
        if (isT0 && isStage0) prcVal = 0.f;
        float cml[R];
#pragma unroll
        for (int r = 0; r < R; r++) {
          float Cv;
          if (isT0) Cv = dl[r][0] + prcVal;
          else      Cv = fmaf(dl[r][comp], Wt[comp], S[r][comp]);
          cml[r] = fminf(Cv, prcMin);
          prcVal = Cv; prcMin = Cv;
        }
        float cmB[R];
#pragma unroll
        for (int r = 0; r < R; r++) cmB[r] = rdlane(cml[r], owner);
        float clastv = rdlane(prcVal, owner);
        if (lane == owner) clast4[comp] = clastv;
#pragma unroll
        for (int k = 0; k < 4; k++) {
          float w_ = wv[tt][k];
          if (w_ > 0.f) {
            float cbv = c[tt][k];
#pragma unroll
            for (int r = 0; r < R; r++) {
              float a = fminf(cmB[r], cbv);
              S[r][k] = fmaf(w_, a, S[r][k]);
              cbv = dl[r][k] + a;
            }
            c[tt][k] = cbv;
          }
        }
      }

      if (w < WV - 1) {
#pragma unroll
        for (int tt = 0; tt < BC; tt++) *(f4*)&LB[w][tt][4 * lane] = c[tt];
        if (lane == 2 * j || lane == 2 * j + 1)
          *(f4*)&crowLB[w][(lane & 1) * 4] = clast4;
      } else if (b < NB - 1) {
        float* b0 = cbarB + (size_t)b * 65536 + j * BC * Nn + 4 * lane;
#pragma unroll
        for (int tt = 0; tt < BC; tt++) llc_store16(b0 + tt * Nn, c[tt]);
        if (lane == 2 * j || lane == 2 * j + 1)
          llc_store16(crowG + b * Nn + j * BC + (lane & 1) * 4, clast4);
        vm_drain();                                     // all data visible at LLC
        if (lane == 0) llc_store_int(flags + b * NCHUNK + j, 1);
      } else {
        // b == NB-1, w == WV-1: fold k_final — accumulate fw[t]*C[M-1][t]
        if (lane == 2 * j || lane == 2 * j + 1) {
          f4 f4v = *(const f4*)(fw + j * BC + (lane & 1) * 4);
          facc += f4v[0] * clast4[0] + f4v[1] * clast4[1]
                + f4v[2] * clast4[2] + f4v[3] * clast4[3];
        }
      }
    }
    __syncthreads();
  }

  if (b == NB - 1 && w == WV - 1) {
#pragma unroll
    for (int off = 32; off > 0; off >>= 1) facc += __shfl_down(facc, off, 64);
    if (lane == 0) out[0] = facc;
  }
}

extern "C" void kernel_launch(void* const* d_in, const int* in_sizes, int n_in,
                              void* d_out, int out_size, void* d_ws, size_t ws_size,
                              hipStream_t stream) {
  const float* x = (const float*)d_in[0];
  const float* y = (const float*)d_in[1];
  const float* q = (const float*)d_in[2];
  float* ws = (float*)d_ws;
  float* out = (float*)d_out;
  hipLaunchKernelGGL(k_setup, dim3(Mm + 257 + 1), dim3(256), 0, stream, x, y, q, ws);
  hipLaunchKernelGGL(k_reach, dim3(1),   dim3(256), 0, stream, ws + OFF_QC, ws + OFF_P);
  hipLaunchKernelGGL(k_wbuild,dim3(Nn),  dim3(Nn),  0, stream, ws + OFF_QC, ws + OFF_P,
                     ws + OFF_WT, ws + OFF_WS, ws + OFF_FW);
  hipLaunchKernelGGL(k_main,  dim3(NB),  dim3(512), 0, stream, ws + OFF_D, ws + OFF_WT,
                     ws + OFF_WS, ws + OFF_FW, ws + OFF_CB, ws + OFF_CROW,
                     (int*)(ws + OFF_FLAG), out);
}

// Round 7
// 28733.453 us; speedup vs baseline: 3.3811x; 3.3811x over previous
//
#include <hip/hip_runtime.h>

typedef float f4 __attribute__((ext_vector_type(4)));

#define Nn 256
#define Mm 512
#define Dd 64
#define EPSF 1e-6f
#define INFF 1e30f
#define BC 8
#define NCHUNK (Nn / BC)   // 32
#define R 8                // rows per wave-stage
#define WV 4               // waves per block
#define NB 16              // blocks (stages = NB*WV = 64)
#define NSLOT (NCHUNK + WV - 1)  // 35
#define NBUF 4             // rotating boundary buffers

// workspace layout (float offsets)
#define OFF_D     0                      // d[m][n]  512*256
#define OFF_QC    131072                 // qc[nb][j]=q[j][nb]  256*257
#define OFF_P     196864                 // p[257] (pad 260)
#define OFF_WT    197124                 // wT[t][n]  256*256
#define OFF_WS    262660                 // W[n] col sums  256
#define OFF_FW    262916                 // fw[t] final weights  256
#define OFF_CB    263172                 // NBUF rotating boundary cbar buffers, each 256*256
#define OFF_CROW  (OFF_CB + NBUF*65536)  // crow[b][256], 16*256
#define OFF_FLAG  (OFF_CROW + NB*Nn)     // flags[b][chunk], 15*32 ints
// total ~530K floats ~2.1 MB (< 2.9 MB proven in R4)

__device__ __forceinline__ float rdlane(float v, int l) {
  return __int_as_float(__builtin_amdgcn_readlane(__float_as_int(v), l));
}

// ---------------- fused setup: dist + q-transpose + flag/Wsum init ----------------
__global__ __launch_bounds__(256) void k_setup(const float* __restrict__ x,
                                               const float* __restrict__ y,
                                               const float* __restrict__ q,
                                               float* __restrict__ ws) {
  int bid = blockIdx.x, tid = threadIdx.x;
  if (bid < Mm) {                      // pairwise L2 distances, row bid
    __shared__ float xs[Dd];
    if (tid < Dd) xs[tid] = x[bid * Dd + tid];
    __syncthreads();
    const float4* y4 = (const float4*)(y + tid * Dd);
    float acc = 0.f;
#pragma unroll
    for (int k = 0; k < Dd / 4; k++) {
      float4 v = y4[k];
      float a0 = xs[4*k+0] - v.x, a1 = xs[4*k+1] - v.y;
      float a2 = xs[4*k+2] - v.z, a3 = xs[4*k+3] - v.w;
      acc += a0*a0 + a1*a1 + a2*a2 + a3*a3;
    }
    ws[OFF_D + bid * Nn + tid] = sqrtf(acc);
  } else if (bid < Mm + 257) {         // transpose q -> qc[nb][j]
    int j = bid - Mm;
    ws[OFF_QC + tid * 257 + j] = q[j * Nn + tid];
  } else {                             // init flags + Wsum
    for (int i = tid; i < (NB - 1) * NCHUNK; i += 256)
      ((int*)(ws + OFF_FLAG))[i] = 0;
    ws[OFF_WS + tid] = 0.f;
  }
}

// blocked sequential reachability scan
__global__ __launch_bounds__(256) void k_reach(const float* __restrict__ qc, float* __restrict__ p_out) {
  __shared__ float p[257];
  __shared__ float vsnap[64];
  __shared__ float qtile[64][65];
  int tid = threadIdx.x;
  p[tid] = (tid == 0) ? 1.f : 0.f;
  if (tid == 0) p[256] = 0.f;
  __syncthreads();
  for (int g = 0; g < 4; g++) {
    int g0 = g * 64;
    for (int z = 0; z < 16; z++) {
      int idx = tid + z * 256, k = idx >> 6, l = idx & 63;
      qtile[k][l] = qc[(g0 + k) * 257 + g0 + l];
    }
    __syncthreads();
    if (tid < 64) {
      float pv = p[g0 + tid];
      for (int k = 0; k < 64; k++) {
        float v = __shfl(pv, k, 64);
        if (tid == k) vsnap[k] = v;
        pv += v * qtile[k][tid];
      }
    }
    __syncthreads();
    float acc = p[tid];
    float acc2 = (tid == 0) ? p[256] : 0.f;
    for (int k = 0; k < 64; k++) {
      float v = vsnap[k];
      acc += v * qc[(g0 + k) * 257 + tid];
      if (tid == 0) acc2 += v * qc[(g0 + k) * 257 + 256];
    }
    __syncthreads();
    p[tid] = acc;
    if (tid == 0) p[256] = acc2;
    __syncthreads();
  }
  p_out[tid] = p[tid];
  if (tid == 0) p_out[256] = p[256];
}

__global__ __launch_bounds__(256) void k_wbuild(const float* __restrict__ qc, const float* __restrict__ p,
                                                float* __restrict__ wT, float* __restrict__ Wsum,
                                                float* __restrict__ fw) {
  int t = blockIdx.x, n = threadIdx.x;
  float v = 0.f;
  if (t < n) v = p[t] * qc[t * 257 + n] / (p[n] + EPSF);
  wT[t * Nn + n] = v;
  if (v != 0.f) atomicAdd(&Wsum[n], v);
  if (n == 0) fw[t] = p[t] * qc[t * 257 + 256] / (p[Nn] + EPSF);
}

// ---------------- main: 16 blocks x 4 wave-stages, LDS systolic in-block,
// cross-block = R1-proven protocol: plain data + atomic release flag / acquire poll.
// NO inline asm anywhere (asm+atomic mixing crashed in R3/R6). ----
__global__ __launch_bounds__(256, 1) void k_main(const float* __restrict__ d,
                                                 const float* __restrict__ wT,
                                                 const float* __restrict__ Wsum,
                                                 const float* __restrict__ fw,
                                                 float* __restrict__ cbarB,
                                                 float* __restrict__ crowG,
                                                 int* __restrict__ flags,
                                                 float* __restrict__ out) {
  const int b = blockIdx.x;
  const int tid = threadIdx.x;
  const int w = tid >> 6;            // wave-stage within block, 0..3
  const int lane = tid & 63;         // owns cols 4*lane..4*lane+3
  const int m0 = (b * WV + w) * R;
  const bool isStage0 = (b == 0 && w == 0);

  __shared__ __align__(16) float LB[WV - 1][BC][Nn];   // 24576 B
  __shared__ __align__(16) float crowLB[WV - 1][BC];

  f4 dl[R], S[R];
#pragma unroll
  for (int r = 0; r < R; r++) {
    dl[r] = *(const f4*)(d + (m0 + r) * Nn + 4 * lane);
    S[r] = (f4){0.f, 0.f, 0.f, 0.f};
  }
  f4 Wt = *(const f4*)(Wsum + 4 * lane);
  float facc = 0.f;                  // final-reduction partial (b==NB-1, w==WV-1)

#pragma clang loop unroll(disable)
  for (int tau = 0; tau < NSLOT; tau++) {
    const int j = tau - w;
    const bool act = (j >= 0 && j < NCHUNK);
    f4 c[BC], cpl, cph, wv[BC];

    // ---- phase 1: acquire input ----
    if (act) {
      if (w == 0) {
        if (b == 0) {
          cpl = (f4){INFF, INFF, INFF, INFF}; cph = cpl;
#pragma unroll
          for (int tt = 0; tt < BC; tt++) c[tt] = cpl;
        } else {
          const int* fp = flags + (b - 1) * NCHUNK + j;
          while (__hip_atomic_load(fp, __ATOMIC_ACQUIRE, __HIP_MEMORY_SCOPE_AGENT) == 0)
            __builtin_amdgcn_s_sleep(8);
          // plain loads — freshness guaranteed by the acquire's invalidate
          const float* src = cbarB + (size_t)((b - 1) & (NBUF - 1)) * 65536
                           + j * BC * Nn + 4 * lane;
#pragma unroll
          for (int tt = 0; tt < BC; tt++) c[tt] = *(const f4*)(src + tt * Nn);
          cpl = *(const f4*)(crowG + (b - 1) * Nn + j * BC);
          cph = *(const f4*)(crowG + (b - 1) * Nn + j * BC + 4);
        }
      } else {
#pragma unroll
        for (int tt = 0; tt < BC; tt++) c[tt] = *(const f4*)&LB[w - 1][tt][4 * lane];
        cpl = *(const f4*)&crowLB[w - 1][0];
        cph = *(const f4*)&crowLB[w - 1][4];
      }
#pragma unroll
      for (int tt = 0; tt < BC; tt++)
        wv[tt] = *(const f4*)(wT + (j * BC + tt) * Nn + 4 * lane);
    }
    __syncthreads();

    // ---- phase 2: compute + hand off ----
    if (act) {
      f4 clast4;
      const bool isJ0 = (j == 0);
#pragma unroll
      for (int tt = 0; tt < BC; tt++) {
        const int owner = 2 * j + (tt >> 2);
        const int comp = tt & 3;
        const bool isT0 = isJ0 && (tt == 0);
        float up = (tt < 4) ? cpl[comp] : cph[comp];
        float prcMin = up, prcVal = up;
        if (isT0 && isStage0) prcVal = 0.f;
        float cml[R];
#pragma unroll
        for (int r = 0; r < R; r++) {
          float Cv;
          if (isT0) Cv = dl[r][0] + prcVal;
          else      Cv = fmaf(dl[r][comp], Wt[comp], S[r][comp]);
          cml[r] = fminf(Cv, prcMin);
          prcVal = Cv; prcMin = Cv;
        }
        float cmB[R];
#pragma unroll
        for (int r = 0; r < R; r++) cmB[r] = rdlane(cml[r], owner);
        float clastv = rdlane(prcVal, owner);
        if (lane == owner) clast4[comp] = clastv;
#pragma unroll
        for (int k = 0; k < 4; k++) {
          float w_ = wv[tt][k];
          if (w_ > 0.f) {
            float cbv = c[tt][k];
#pragma unroll
            for (int r = 0; r < R; r++) {
              float a = fminf(cmB[r], cbv);
              S[r][k] = fmaf(w_, a, S[r][k]);
              cbv = dl[r][k] + a;
            }
            c[tt][k] = cbv;
          }
        }
      }

      if (w < WV - 1) {
#pragma unroll
        for (int tt = 0; tt < BC; tt++) *(f4*)&LB[w][tt][4 * lane] = c[tt];
        if (lane == 2 * j || lane == 2 * j + 1)
          *(f4*)&crowLB[w][(lane & 1) * 4] = clast4;
      } else if (b < NB - 1) {
        // plain stores; the release below orders + flushes them to LLC
        float* b0 = cbarB + (size_t)(b & (NBUF - 1)) * 65536 + j * BC * Nn + 4 * lane;
#pragma unroll
        for (int tt = 0; tt < BC; tt++) *(f4*)(b0 + tt * Nn) = c[tt];
        if (lane == 2 * j || lane == 2 * j + 1)
          *(f4*)(crowG + b * Nn + j * BC + (lane & 1) * 4) = clast4;
        if (lane == 0)
          __hip_atomic_store(flags + b * NCHUNK + j, 1, __ATOMIC_RELEASE,
                             __HIP_MEMORY_SCOPE_AGENT);
      } else {
        // b == NB-1, w == WV-1: fold k_final — accumulate fw[t]*C[M-1][t]
        if (lane == 2 * j || lane == 2 * j + 1) {
          f4 f4v = *(const f4*)(fw + j * BC + (lane & 1) * 4);
          facc += f4v[0] * clast4[0] + f4v[1] * clast4[1]
                + f4v[2] * clast4[2] + f4v[3] * clast4[3];
        }
      }
    }
    __syncthreads();
  }

  if (b == NB - 1 && w == WV - 1) {
#pragma unroll
    for (int off = 32; off > 0; off >>= 1) facc += __shfl_down(facc, off, 64);
    if (lane == 0) out[0] = facc;
  }
}

extern "C" void kernel_launch(void* const* d_in, const int* in_sizes, int n_in,
                              void* d_out, int out_size, void* d_ws, size_t ws_size,
                              hipStream_t stream) {
  const float* x = (const float*)d_in[0];
  const float* y = (const float*)d_in[1];
  const float* q = (const float*)d_in[2];
  float* ws = (float*)d_ws;
  float* out = (float*)d_out;
  hipLaunchKernelGGL(k_setup, dim3(Mm + 257 + 1), dim3(256), 0, stream, x, y, q, ws);
  hipLaunchKernelGGL(k_reach, dim3(1),   dim3(256), 0, stream, ws + OFF_QC, ws + OFF_P);
  hipLaunchKernelGGL(k_wbuild,dim3(Nn),  dim3(Nn),  0, stream, ws + OFF_QC, ws + OFF_P,
                     ws + OFF_WT, ws + OFF_WS, ws + OFF_FW);
  hipLaunchKernelGGL(k_main,  dim3(NB),  dim3(256), 0, stream, ws + OFF_D, ws + OFF_WT,
                     ws + OFF_WS, ws + OFF_FW, ws + OFF_CB, ws + OFF_CROW,
                     (int*)(ws + OFF_FLAG), out);
}